// Round 18
// baseline (78.887 us; speedup 1.0000x reference)
//
#include <hip/hip_runtime.h>

#define QTOT 12240
#define KD   256

typedef float f32x4 __attribute__((ext_vector_type(4)));
typedef short s16x8 __attribute__((ext_vector_type(8)));
typedef short s16x4 __attribute__((ext_vector_type(4)));
typedef unsigned short ushort_t;

__device__ __forceinline__ unsigned short f2b(float x) {
    union { float f; unsigned u; } c; c.f = x;
    unsigned r = c.u + 0x7fffu + ((c.u >> 16) & 1u);
    return (unsigned short)(r >> 16);
}
__device__ __forceinline__ float b2f(unsigned short u) {
    return __uint_as_float((unsigned)u << 16);
}
// LDS row: 512B, XOR bits 4-6 of k-byte with row&7 (write & read sides).
__device__ __forceinline__ int swz(int row, int kb) { return row * 512 + (kb ^ ((row & 7) << 4)); }

// ---------------------------------------------------------------------------
// prep2: coalesced weight transpose via 32x32 LDS tiles + combined bias.
// ---------------------------------------------------------------------------
__global__ __launch_bounds__(256) void prep2(
    const float* __restrict__ W_val, const float* __restrict__ W_off,
    const float* __restrict__ W_attn, const float* __restrict__ W_out,
    const float* __restrict__ b_off, const float* __restrict__ b_attn,
    ushort_t* __restrict__ WvT, ushort_t* __restrict__ WcT,
    ushort_t* __restrict__ WoT, float* __restrict__ bcomb)
{
    const int b = blockIdx.x;
    if (b == 224) {
        for (int t = threadIdx.x; t < 384; t += 256)
            bcomb[t] = (t < 256) ? b_off[t] : b_attn[t - 256];
        return;
    }
    __shared__ ushort_t tile[32][33];
    const float* src; ushort_t* dst; int kt, nt, srcld, n_off;
    if (b < 64)       { src = W_val; dst = WvT; kt = b >> 3; nt = b & 7; srcld = 256; n_off = 0; }
    else if (b < 160) { int t = b - 64; dst = WcT; kt = t / 12; nt = t % 12;
                        if (nt < 8) { src = W_off;  srcld = 256; n_off = 0; }
                        else        { src = W_attn; srcld = 128; n_off = 256; } }
    else              { int t = b - 160; src = W_out; dst = WoT; kt = t >> 3; nt = t & 7; srcld = 256; n_off = 0; }

    {   // read 32x32 tile, rows coalesced
        const int r = threadIdx.x >> 3, c4 = (threadIdx.x & 7) * 4;
        const int gk = kt * 32 + r;
        const int gs = nt * 32 + c4 - n_off;
        float4 f = *(const float4*)(src + (size_t)gk * srcld + gs);
        tile[r][c4 + 0] = f2b(f.x); tile[r][c4 + 1] = f2b(f.y);
        tile[r][c4 + 2] = f2b(f.z); tile[r][c4 + 3] = f2b(f.w);
    }
    __syncthreads();
    {   // write transposed, rows coalesced
        const int r2 = threadIdx.x >> 3, k4 = (threadIdx.x & 7) * 4;
        s16x4 v;
        v[0] = tile[k4 + 0][r2]; v[1] = tile[k4 + 1][r2];
        v[2] = tile[k4 + 2][r2]; v[3] = tile[k4 + 3][r2];
        *(s16x4*)(dst + (size_t)(nt * 32 + r2) * 256 + kt * 32 + k4) = v;
    }
}

// ---------------------------------------------------------------------------
// gemm1 chunk body: optional prefetch of next chunk's B, 16 MFMA from LDS A,
// epilogue (proj/off stores, or fused softmax -> attnb for attn chunks).
// cur/nxt are distinct named register arrays (no runtime indexing).
// ---------------------------------------------------------------------------
template<bool ISVAL>
__device__ __forceinline__ void g1chunk(
    int c, bool pre, const char* As, const ushort_t* __restrict__ WT,
    const float* __restrict__ bias, ushort_t* __restrict__ projb,
    ushort_t* __restrict__ offb, ushort_t* __restrict__ attnb,
    int bm, s16x8 (&cur)[8], s16x8 (&nxt)[8])
{
    const int tid = threadIdx.x, lane = tid & 63, wave = tid >> 6;
    const int lr = lane & 15, g8 = (lane >> 4) * 8, rg = (lane >> 4) * 4;

    if (pre) {
        const ushort_t* bp = WT + (size_t)((c + 1) * 64 + wave * 16 + lr) * KD + g8;
#pragma unroll
        for (int kc = 0; kc < 8; ++kc) nxt[kc] = *(const s16x8*)(bp + kc * 32);
    }

    f32x4 acc0 = (f32x4)0.f, acc1 = (f32x4)0.f;
#pragma unroll
    for (int kc = 0; kc < 8; ++kc) {
        const int kb = (kc * 32 + g8) * 2;
        s16x8 a0 = *(const s16x8*)(As + swz(lr,      kb));
        s16x8 a1 = *(const s16x8*)(As + swz(16 + lr, kb));
        acc0 = __builtin_amdgcn_mfma_f32_16x16x32_bf16(a0, cur[kc], acc0, 0, 0, 0);
        acc1 = __builtin_amdgcn_mfma_f32_16x16x32_bf16(a1, cur[kc], acc1, 0, 0, 0);
    }

    const int col = c * 64 + wave * 16 + lr;
    const float bb = bias[col];

    if (!ISVAL && c >= 4) {
        // fused softmax over the 16-lane group (cols of one head)
        const int gh = (c - 4) * 4 + wave;       // global head 0..7
        float v[2][4], m[2][4], e[2][4], s[2][4];
#pragma unroll
        for (int rr = 0; rr < 4; ++rr) { v[0][rr] = acc0[rr] + bb; v[1][rr] = acc1[rr] + bb; }
#pragma unroll
        for (int mf = 0; mf < 2; ++mf)
#pragma unroll
            for (int rr = 0; rr < 4; ++rr) m[mf][rr] = v[mf][rr];
#pragma unroll
        for (int d = 1; d < 16; d <<= 1)
#pragma unroll
            for (int mf = 0; mf < 2; ++mf)
#pragma unroll
                for (int rr = 0; rr < 4; ++rr) m[mf][rr] = fmaxf(m[mf][rr], __shfl_xor(m[mf][rr], d));
#pragma unroll
        for (int mf = 0; mf < 2; ++mf)
#pragma unroll
            for (int rr = 0; rr < 4; ++rr) { e[mf][rr] = __expf(v[mf][rr] - m[mf][rr]); s[mf][rr] = e[mf][rr]; }
#pragma unroll
        for (int d = 1; d < 16; d <<= 1)
#pragma unroll
            for (int mf = 0; mf < 2; ++mf)
#pragma unroll
                for (int rr = 0; rr < 4; ++rr) s[mf][rr] += __shfl_xor(s[mf][rr], d);
#pragma unroll
        for (int mf = 0; mf < 2; ++mf)
#pragma unroll
            for (int rr = 0; rr < 4; ++rr) {
                const int row = bm + mf * 16 + rg + rr;
                if (row < QTOT)
                    attnb[(size_t)row * 128 + gh * 16 + lr] = f2b(e[mf][rr] / s[mf][rr]);
            }
    } else {
#pragma unroll
        for (int mf = 0; mf < 2; ++mf) {
            const f32x4& a = mf ? acc1 : acc0;
#pragma unroll
            for (int rr = 0; rr < 4; ++rr) {
                const int row = bm + mf * 16 + rg + rr;
                if (row >= QTOT) continue;
                const float v = a[rr] + bb;
                if (ISVAL) projb[(size_t)row * 256 + col] = f2b(v);
                else       offb [(size_t)row * 256 + col] = f2b(v);
            }
        }
    }
}

// ---------------------------------------------------------------------------
// gemm1: BM=32, grid 766, A-read-once, 1 barrier, fused softmax epilogue,
// B in registers DOUBLE-BUFFERED (chunk 0's B load hides under A staging,
// chunk c+1's B load hides under chunk c's MFMA).
// ---------------------------------------------------------------------------
__global__ __launch_bounds__(256) void gemm1(
    const float* __restrict__ inflat, const float* __restrict__ query,
    const ushort_t* __restrict__ WvT, const ushort_t* __restrict__ WcT,
    const float* __restrict__ b_val, const float* __restrict__ bcomb,
    ushort_t* __restrict__ projb, ushort_t* __restrict__ offb,
    ushort_t* __restrict__ attnb)
{
    __shared__ char As[16384];
    const int b = blockIdx.x;
    const bool isval = b < 383;
    const int bm = (isval ? b : b - 383) * 32;
    const float* A = isval ? inflat : query;
    const ushort_t* WT = isval ? WvT : WcT;

    const int tid = threadIdx.x, lane = tid & 63, wave = tid >> 6;
    const int lr = lane & 15, g8 = (lane >> 4) * 8;

    s16x8 b0[8], b1[8];
    {   // prefetch chunk 0's B (hides under A staging)
        const ushort_t* bp = WT + (size_t)(wave * 16 + lr) * KD + g8;
#pragma unroll
        for (int kc = 0; kc < 8; ++kc) b0[kc] = *(const s16x8*)(bp + kc * 32);
    }

    {   // stage A panel: 32 rows x 256 k, f32 -> bf16; linear coalesced map
        const float4* srcb = (const float4*)(A + (size_t)bm * KD);
        const int rem_rows = QTOT - bm;
#pragma unroll
        for (int j = 0; j < 8; ++j) {
            const int f4i = j * 256 + tid;
            const int row = f4i >> 6;
            const int colb = (f4i & 63) * 8;
            float4 f = make_float4(0.f, 0.f, 0.f, 0.f);
            if (row < rem_rows) f = srcb[f4i];
            s16x4 v;
            v[0] = f2b(f.x); v[1] = f2b(f.y); v[2] = f2b(f.z); v[3] = f2b(f.w);
            *(s16x4*)(As + swz(row, colb)) = v;
        }
    }
    __syncthreads();

    if (isval) {
        g1chunk<true>(0, true,  As, WT, b_val, projb, offb, attnb, bm, b0, b1);
        g1chunk<true>(1, true,  As, WT, b_val, projb, offb, attnb, bm, b1, b0);
        g1chunk<true>(2, true,  As, WT, b_val, projb, offb, attnb, bm, b0, b1);
        g1chunk<true>(3, false, As, WT, b_val, projb, offb, attnb, bm, b1, b0);
    } else {
        g1chunk<false>(0, true,  As, WT, bcomb, projb, offb, attnb, bm, b0, b1);
        g1chunk<false>(1, true,  As, WT, bcomb, projb, offb, attnb, bm, b1, b0);
        g1chunk<false>(2, true,  As, WT, bcomb, projb, offb, attnb, bm, b0, b1);
        g1chunk<false>(3, true,  As, WT, bcomb, projb, offb, attnb, bm, b1, b0);
        g1chunk<false>(4, true,  As, WT, bcomb, projb, offb, attnb, bm, b0, b1);
        g1chunk<false>(5, false, As, WT, bcomb, projb, offb, attnb, bm, b1, b0);
    }
}

// ---------------------------------------------------------------------------
// sample7: unchanged (packed int4 metadata, head-half split,
// launch_bounds(256,2), hardcoded spatial shapes).
// ---------------------------------------------------------------------------
__global__ __launch_bounds__(256, 2) void sample7(
    const float* __restrict__ rp, const ushort_t* __restrict__ offb,
    const ushort_t* __restrict__ attnb, const ushort_t* __restrict__ projb,
    ushort_t* __restrict__ outpre)
{
    const int bid = blockIdx.x;
    const int hh = (bid >= 1530) ? 1 : 0;       // head-half (slow index)
    const int g  = hh ? (bid - 1530) : bid;     // query group
    const int q0 = g * 8;
    const int tid = threadIdx.x;

    __shared__ int4 s_meta[512];                // [ql][hp][lp] packed corners

#pragma unroll
    for (int rep = 0; rep < 2; ++rep) {
        const int task = rep * 256 + tid;
        const int ql = task >> 6;
        const int hp = (task >> 4) & 3;
        const int lp = task & 15;
        const int l = lp >> 2;
        const int q = q0 + ql;
        const int gh = hh * 4 + hp;
        const int t128 = gh * 16 + lp;

        const float aw = b2f(attnb[(size_t)q * 128 + t128]);

        const unsigned opk = *(const unsigned*)&offb[(size_t)q * 256 + t128 * 2];
        const float ox = __uint_as_float(opk << 16);
        const float oy = __uint_as_float(opk & 0xffff0000u);

        const int Wl = 96 >> l;                  // = Hl (fixed problem shapes)
        const int st = 12288 - (12288 >> (2 * l));
        const float rx = rp[((size_t)q * 4 + l) * 2 + 0];
        const float ry = rp[((size_t)q * 4 + l) * 2 + 1];

        const float x = rx * (float)Wl + ox - 0.5f;
        const float y = ry * (float)Wl + oy - 0.5f;
        const float xf = floorf(x), yf = floorf(y);
        const int x0 = (int)xf, y0 = (int)yf;
        const float lx = x - xf, ly = y - yf;

        const bool vx0 = (x0 >= 0) && (x0 < Wl);
        const bool vx1 = (x0 + 1 >= 0) && (x0 + 1 < Wl);
        const bool vy0 = (y0 >= 0) && (y0 < Wl);
        const bool vy1 = (y0 + 1 >= 0) && (y0 + 1 < Wl);

        const float w00 = (vx0 && vy0) ? aw * (1.f - ly) * (1.f - lx) : 0.f;
        const float w01 = (vx1 && vy0) ? aw * (1.f - ly) * lx         : 0.f;
        const float w10 = (vx0 && vy1) ? aw * ly * (1.f - lx)         : 0.f;
        const float w11 = (vx1 && vy1) ? aw * ly * lx                 : 0.f;
        const int i00 = (vx0 && vy0) ? st + y0 * Wl + x0           : 0;
        const int i01 = (vx1 && vy0) ? st + y0 * Wl + x0 + 1       : 0;
        const int i10 = (vx0 && vy1) ? st + (y0 + 1) * Wl + x0     : 0;
        const int i11 = (vx1 && vy1) ? st + (y0 + 1) * Wl + x0 + 1 : 0;

        int4 m;
        m.x = (i00 << 16) | (int)f2b(w00);
        m.y = (i01 << 16) | (int)f2b(w01);
        m.z = (i10 << 16) | (int)f2b(w10);
        m.w = (i11 << 16) | (int)f2b(w11);
        s_meta[task] = m;
    }
    __syncthreads();

    const int c8 = tid & 3;
    const int pq = (tid >> 2) & 1;
    const int hp = (tid >> 3) & 3;
    const int ql = tid >> 5;
    const int gh = hh * 4 + hp;
    const char* basec = (const char*)projb + (gh * 32 + c8 * 8) * 2;
    const int slot0 = (ql << 6) | (hp << 4);

    float a0 = 0, a1 = 0, a2 = 0, a3 = 0, a4 = 0, a5 = 0, a6 = 0, a7 = 0;
#pragma unroll
    for (int l = 0; l < 4; ++l) {
#pragma unroll
        for (int j = 0; j < 2; ++j) {
            const int slot = slot0 | (l << 2) | (pq * 2 + j);
            const int4 m = s_meta[slot];
#pragma unroll
            for (int c = 0; c < 4; ++c) {
                const int pk = (c == 0) ? m.x : (c == 1) ? m.y : (c == 2) ? m.z : m.w;
                const int off = (pk >> 16) << 9;
                const float w = __uint_as_float((unsigned)pk << 16);
                const uint4 v = *(const uint4*)(basec + off);
                a0 += w * __uint_as_float(v.x << 16);
                a1 += w * __uint_as_float(v.x & 0xffff0000u);
                a2 += w * __uint_as_float(v.y << 16);
                a3 += w * __uint_as_float(v.y & 0xffff0000u);
                a4 += w * __uint_as_float(v.z << 16);
                a5 += w * __uint_as_float(v.z & 0xffff0000u);
                a6 += w * __uint_as_float(v.w << 16);
                a7 += w * __uint_as_float(v.w & 0xffff0000u);
            }
        }
    }
    a0 += __shfl_xor(a0, 4); a1 += __shfl_xor(a1, 4);
    a2 += __shfl_xor(a2, 4); a3 += __shfl_xor(a3, 4);
    a4 += __shfl_xor(a4, 4); a5 += __shfl_xor(a5, 4);
    a6 += __shfl_xor(a6, 4); a7 += __shfl_xor(a7, 4);

    if (pq == 0) {
        uint4 o;
        o.x = (unsigned)f2b(a0) | ((unsigned)f2b(a1) << 16);
        o.y = (unsigned)f2b(a2) | ((unsigned)f2b(a3) << 16);
        o.z = (unsigned)f2b(a4) | ((unsigned)f2b(a5) << 16);
        o.w = (unsigned)f2b(a6) | ((unsigned)f2b(a7) << 16);
        *(uint4*)&outpre[(size_t)(q0 + ql) * 256 + gh * 32 + c8 * 8] = o;
    }
}

// ---------------------------------------------------------------------------
// gemm_o: unchanged champion (LDS-free, barrier-free, BM=32, N=256).
// ---------------------------------------------------------------------------
__global__ __launch_bounds__(256) void gemm_o(
    const ushort_t* __restrict__ Ab, const ushort_t* __restrict__ WoT,
    const float* __restrict__ b_out, float* __restrict__ out)
{
    const int bm = blockIdx.x * 32;
    const int tid = threadIdx.x, lane = tid & 63, wave = tid >> 6;
    const int lr = lane & 15, g8 = (lane >> 4) * 8;
    const int rg = (lane >> 4) * 4;

    const ushort_t* ap0;
    const ushort_t* ap1;
    {
        int r0 = bm + lr;      if (r0 >= QTOT) r0 = QTOT - 1;
        int r1 = bm + 16 + lr; if (r1 >= QTOT) r1 = QTOT - 1;
        ap0 = Ab + (size_t)r0 * KD + g8;
        ap1 = Ab + (size_t)r1 * KD + g8;
    }

#pragma unroll
    for (int c = 0; c < 4; ++c) {
        const int col = c * 64 + wave * 16 + lr;
        s16x8 bfr[8];
        {
            const ushort_t* bp = WoT + (size_t)col * KD + g8;
#pragma unroll
            for (int kc = 0; kc < 8; ++kc) bfr[kc] = *(const s16x8*)(bp + kc * 32);
        }
        f32x4 acc[2];
        acc[0] = (f32x4)0.f; acc[1] = (f32x4)0.f;
#pragma unroll
        for (int kc = 0; kc < 8; ++kc) {
            s16x8 a0 = *(const s16x8*)(ap0 + kc * 32);
            s16x8 a1 = *(const s16x8*)(ap1 + kc * 32);
            acc[0] = __builtin_amdgcn_mfma_f32_16x16x32_bf16(a0, bfr[kc], acc[0], 0, 0, 0);
            acc[1] = __builtin_amdgcn_mfma_f32_16x16x32_bf16(a1, bfr[kc], acc[1], 0, 0, 0);
        }
        const float bb = b_out[col];
#pragma unroll
        for (int mf = 0; mf < 2; ++mf)
#pragma unroll
            for (int rr = 0; rr < 4; ++rr) {
                const int row = bm + mf * 16 + rg + rr;
                if (row < QTOT) out[(size_t)row * 256 + col] = acc[mf][rr] + bb;
            }
    }
}

// ---------------------------------------------------------------------------
extern "C" void kernel_launch(void* const* d_in, const int* in_sizes, int n_in,
                              void* d_out, int out_size, void* d_ws, size_t ws_size,
                              hipStream_t stream) {
    const float* query  = (const float*)d_in[0];
    const float* rp     = (const float*)d_in[1];
    const float* inflat = (const float*)d_in[2];
    const float* W_off  = (const float*)d_in[5];
    const float* b_off  = (const float*)d_in[6];
    const float* W_attn = (const float*)d_in[7];
    const float* b_attn = (const float*)d_in[8];
    const float* W_val  = (const float*)d_in[9];
    const float* b_val  = (const float*)d_in[10];
    const float* W_out  = (const float*)d_in[11];
    const float* b_out  = (const float*)d_in[12];
    float* out = (float*)d_out;

    char* ws = (char*)d_ws;
    ushort_t* projb  = (ushort_t*)ws; ws += (size_t)QTOT * 256 * 2;
    ushort_t* offb   = (ushort_t*)ws; ws += (size_t)QTOT * 256 * 2;
    ushort_t* attnb  = (ushort_t*)ws; ws += (size_t)QTOT * 128 * 2;
    ushort_t* outpre = (ushort_t*)ws; ws += (size_t)QTOT * 256 * 2;
    ushort_t* WvT    = (ushort_t*)ws; ws += 65536 * 2;
    ushort_t* WcT    = (ushort_t*)ws; ws += 98304 * 2;
    ushort_t* WoT    = (ushort_t*)ws; ws += 65536 * 2;
    float*    bcomb  = (float*)ws;    ws += 384 * 4;

    prep2<<<dim3(225), dim3(256), 0, stream>>>(W_val, W_off, W_attn, W_out, b_off, b_attn,
                                               WvT, WcT, WoT, bcomb);

    gemm1<<<dim3(766), dim3(256), 0, stream>>>(inflat, query, WvT, WcT, b_val, bcomb,
                                               projb, offb, attnb);

    sample7<<<dim3(3060), dim3(256), 0, stream>>>(rp, offb, attnb, projb, outpre);

    gemm_o<<<dim3(383), dim3(256), 0, stream>>>(outpre, WoT, b_out, out);
}

// Round 19
// 66.893 us; speedup vs baseline: 1.1793x; 1.1793x over previous
//
#include <hip/hip_runtime.h>

#define QTOT 12240
#define KD   256

typedef float f32x4 __attribute__((ext_vector_type(4)));
typedef short s16x8 __attribute__((ext_vector_type(8)));
typedef short s16x4 __attribute__((ext_vector_type(4)));
typedef unsigned short ushort_t;

__device__ __forceinline__ unsigned short f2b(float x) {
    union { float f; unsigned u; } c; c.f = x;
    unsigned r = c.u + 0x7fffu + ((c.u >> 16) & 1u);
    return (unsigned short)(r >> 16);
}
__device__ __forceinline__ float b2f(unsigned short u) {
    return __uint_as_float((unsigned)u << 16);
}
// LDS row: 512B, XOR bits 4-6 of k-byte with row&7 (write & read sides).
__device__ __forceinline__ int swz(int row, int kb) { return row * 512 + (kb ^ ((row & 7) << 4)); }

// ---------------------------------------------------------------------------
// prep2: coalesced weight transpose via 32x32 LDS tiles + combined bias.
// ---------------------------------------------------------------------------
__global__ __launch_bounds__(256) void prep2(
    const float* __restrict__ W_val, const float* __restrict__ W_off,
    const float* __restrict__ W_attn, const float* __restrict__ W_out,
    const float* __restrict__ b_off, const float* __restrict__ b_attn,
    ushort_t* __restrict__ WvT, ushort_t* __restrict__ WcT,
    ushort_t* __restrict__ WoT, float* __restrict__ bcomb)
{
    const int b = blockIdx.x;
    if (b == 224) {
        for (int t = threadIdx.x; t < 384; t += 256)
            bcomb[t] = (t < 256) ? b_off[t] : b_attn[t - 256];
        return;
    }
    __shared__ ushort_t tile[32][33];
    const float* src; ushort_t* dst; int kt, nt, srcld, n_off;
    if (b < 64)       { src = W_val; dst = WvT; kt = b >> 3; nt = b & 7; srcld = 256; n_off = 0; }
    else if (b < 160) { int t = b - 64; dst = WcT; kt = t / 12; nt = t % 12;
                        if (nt < 8) { src = W_off;  srcld = 256; n_off = 0; }
                        else        { src = W_attn; srcld = 128; n_off = 256; } }
    else              { int t = b - 160; src = W_out; dst = WoT; kt = t >> 3; nt = t & 7; srcld = 256; n_off = 0; }

    {   // read 32x32 tile, rows coalesced
        const int r = threadIdx.x >> 3, c4 = (threadIdx.x & 7) * 4;
        const int gk = kt * 32 + r;
        const int gs = nt * 32 + c4 - n_off;
        float4 f = *(const float4*)(src + (size_t)gk * srcld + gs);
        tile[r][c4 + 0] = f2b(f.x); tile[r][c4 + 1] = f2b(f.y);
        tile[r][c4 + 2] = f2b(f.z); tile[r][c4 + 3] = f2b(f.w);
    }
    __syncthreads();
    {   // write transposed, rows coalesced
        const int r2 = threadIdx.x >> 3, k4 = (threadIdx.x & 7) * 4;
        s16x4 v;
        v[0] = tile[k4 + 0][r2]; v[1] = tile[k4 + 1][r2];
        v[2] = tile[k4 + 2][r2]; v[3] = tile[k4 + 3][r2];
        *(s16x4*)(dst + (size_t)(nt * 32 + r2) * 256 + kt * 32 + k4) = v;
    }
}

// ---------------------------------------------------------------------------
// gemm1: BM=48, grid 510 = 255 val + 255 cmb (12240 = 255*48 exactly — no
// row bounds checks). A-read-once (48x256 panel, 24KB LDS, 1 barrier),
// B-in-registers single-buffered (serial chunk loop — dbuf proven toxic,
// R18: vmcnt drain serializes the prefetch). 3 m-frags/wave: each 8-load
// B-chain feeds 24 MFMAs. Fused softmax epilogue for attn chunks.
// ---------------------------------------------------------------------------
__global__ __launch_bounds__(256) void gemm1(
    const float* __restrict__ inflat, const float* __restrict__ query,
    const ushort_t* __restrict__ WvT, const ushort_t* __restrict__ WcT,
    const float* __restrict__ b_val, const float* __restrict__ bcomb,
    ushort_t* __restrict__ projb, ushort_t* __restrict__ offb,
    ushort_t* __restrict__ attnb)
{
    __shared__ char As[24576];
    const int b = blockIdx.x;
    const bool isval = b < 255;
    const int bm = (isval ? b : b - 255) * 48;
    const float* A = isval ? inflat : query;
    const ushort_t* WT = isval ? WvT : WcT;
    const int nc = isval ? 4 : 6;

    const int tid = threadIdx.x, lane = tid & 63, wave = tid >> 6;
    const int lr = lane & 15, g8 = (lane >> 4) * 8;

    {   // stage A panel: 48 rows x 256 k, f32 -> bf16; linear coalesced map
        const float4* srcb = (const float4*)(A + (size_t)bm * KD);
#pragma unroll
        for (int j = 0; j < 12; ++j) {
            const int f4i = j * 256 + tid;
            const int row = f4i >> 6;                 // wave-uniform per 64-thread group
            const int colb = (f4i & 63) * 8;
            float4 f = srcb[f4i];
            s16x4 v;
            v[0] = f2b(f.x); v[1] = f2b(f.y); v[2] = f2b(f.z); v[3] = f2b(f.w);
            *(s16x4*)(As + swz(row, colb)) = v;
        }
    }
    __syncthreads();

    const int rg = (lane >> 4) * 4;

    for (int c = 0; c < nc; ++c) {
        const int col = c * 64 + wave * 16 + lr;
        s16x8 bfr[8];
        {
            const ushort_t* bp = WT + (size_t)col * KD + g8;
#pragma unroll
            for (int kc = 0; kc < 8; ++kc) bfr[kc] = *(const s16x8*)(bp + kc * 32);
        }
        f32x4 acc0 = (f32x4)0.f, acc1 = (f32x4)0.f, acc2 = (f32x4)0.f;
#pragma unroll
        for (int kc = 0; kc < 8; ++kc) {
            const int kb = (kc * 32 + g8) * 2;
            s16x8 a0 = *(const s16x8*)(As + swz(lr,      kb));
            s16x8 a1 = *(const s16x8*)(As + swz(16 + lr, kb));
            s16x8 a2 = *(const s16x8*)(As + swz(32 + lr, kb));
            acc0 = __builtin_amdgcn_mfma_f32_16x16x32_bf16(a0, bfr[kc], acc0, 0, 0, 0);
            acc1 = __builtin_amdgcn_mfma_f32_16x16x32_bf16(a1, bfr[kc], acc1, 0, 0, 0);
            acc2 = __builtin_amdgcn_mfma_f32_16x16x32_bf16(a2, bfr[kc], acc2, 0, 0, 0);
        }
        const float bb = isval ? b_val[col] : bcomb[col];

        if (!isval && c >= 4) {
            // ---- fused softmax over the 16-lane group (cols of one head) ----
            const int gh = (c - 4) * 4 + wave;       // global head 0..7
            float v[3][4], m[3][4], e[3][4], s[3][4];
#pragma unroll
            for (int rr = 0; rr < 4; ++rr) {
                v[0][rr] = acc0[rr] + bb; v[1][rr] = acc1[rr] + bb; v[2][rr] = acc2[rr] + bb;
            }
#pragma unroll
            for (int mf = 0; mf < 3; ++mf)
#pragma unroll
                for (int rr = 0; rr < 4; ++rr) m[mf][rr] = v[mf][rr];
#pragma unroll
            for (int d = 1; d < 16; d <<= 1)
#pragma unroll
                for (int mf = 0; mf < 3; ++mf)
#pragma unroll
                    for (int rr = 0; rr < 4; ++rr) m[mf][rr] = fmaxf(m[mf][rr], __shfl_xor(m[mf][rr], d));
#pragma unroll
            for (int mf = 0; mf < 3; ++mf)
#pragma unroll
                for (int rr = 0; rr < 4; ++rr) { e[mf][rr] = __expf(v[mf][rr] - m[mf][rr]); s[mf][rr] = e[mf][rr]; }
#pragma unroll
            for (int d = 1; d < 16; d <<= 1)
#pragma unroll
                for (int mf = 0; mf < 3; ++mf)
#pragma unroll
                    for (int rr = 0; rr < 4; ++rr) s[mf][rr] += __shfl_xor(s[mf][rr], d);
#pragma unroll
            for (int mf = 0; mf < 3; ++mf)
#pragma unroll
                for (int rr = 0; rr < 4; ++rr)
                    attnb[(size_t)(bm + mf * 16 + rg + rr) * 128 + gh * 16 + lr] =
                        f2b(e[mf][rr] / s[mf][rr]);
        } else {
#pragma unroll
            for (int mf = 0; mf < 3; ++mf) {
                const f32x4& a = (mf == 0) ? acc0 : (mf == 1) ? acc1 : acc2;
#pragma unroll
                for (int rr = 0; rr < 4; ++rr) {
                    const int row = bm + mf * 16 + rg + rr;
                    const float v = a[rr] + bb;
                    if (isval) projb[(size_t)row * 256 + col] = f2b(v);
                    else       offb [(size_t)row * 256 + col] = f2b(v);
                }
            }
        }
    }
}

// ---------------------------------------------------------------------------
// sample7: unchanged (packed int4 metadata, head-half split,
// launch_bounds(256,2), hardcoded spatial shapes).
// ---------------------------------------------------------------------------
__global__ __launch_bounds__(256, 2) void sample7(
    const float* __restrict__ rp, const ushort_t* __restrict__ offb,
    const ushort_t* __restrict__ attnb, const ushort_t* __restrict__ projb,
    ushort_t* __restrict__ outpre)
{
    const int bid = blockIdx.x;
    const int hh = (bid >= 1530) ? 1 : 0;       // head-half (slow index)
    const int g  = hh ? (bid - 1530) : bid;     // query group
    const int q0 = g * 8;
    const int tid = threadIdx.x;

    __shared__ int4 s_meta[512];                // [ql][hp][lp] packed corners

#pragma unroll
    for (int rep = 0; rep < 2; ++rep) {
        const int task = rep * 256 + tid;
        const int ql = task >> 6;
        const int hp = (task >> 4) & 3;
        const int lp = task & 15;
        const int l = lp >> 2;
        const int q = q0 + ql;
        const int gh = hh * 4 + hp;
        const int t128 = gh * 16 + lp;

        const float aw = b2f(attnb[(size_t)q * 128 + t128]);

        const unsigned opk = *(const unsigned*)&offb[(size_t)q * 256 + t128 * 2];
        const float ox = __uint_as_float(opk << 16);
        const float oy = __uint_as_float(opk & 0xffff0000u);

        const int Wl = 96 >> l;                  // = Hl (fixed problem shapes)
        const int st = 12288 - (12288 >> (2 * l));
        const float rx = rp[((size_t)q * 4 + l) * 2 + 0];
        const float ry = rp[((size_t)q * 4 + l) * 2 + 1];

        const float x = rx * (float)Wl + ox - 0.5f;
        const float y = ry * (float)Wl + oy - 0.5f;
        const float xf = floorf(x), yf = floorf(y);
        const int x0 = (int)xf, y0 = (int)yf;
        const float lx = x - xf, ly = y - yf;

        const bool vx0 = (x0 >= 0) && (x0 < Wl);
        const bool vx1 = (x0 + 1 >= 0) && (x0 + 1 < Wl);
        const bool vy0 = (y0 >= 0) && (y0 < Wl);
        const bool vy1 = (y0 + 1 >= 0) && (y0 + 1 < Wl);

        const float w00 = (vx0 && vy0) ? aw * (1.f - ly) * (1.f - lx) : 0.f;
        const float w01 = (vx1 && vy0) ? aw * (1.f - ly) * lx         : 0.f;
        const float w10 = (vx0 && vy1) ? aw * ly * (1.f - lx)         : 0.f;
        const float w11 = (vx1 && vy1) ? aw * ly * lx                 : 0.f;
        const int i00 = (vx0 && vy0) ? st + y0 * Wl + x0           : 0;
        const int i01 = (vx1 && vy0) ? st + y0 * Wl + x0 + 1       : 0;
        const int i10 = (vx0 && vy1) ? st + (y0 + 1) * Wl + x0     : 0;
        const int i11 = (vx1 && vy1) ? st + (y0 + 1) * Wl + x0 + 1 : 0;

        int4 m;
        m.x = (i00 << 16) | (int)f2b(w00);
        m.y = (i01 << 16) | (int)f2b(w01);
        m.z = (i10 << 16) | (int)f2b(w10);
        m.w = (i11 << 16) | (int)f2b(w11);
        s_meta[task] = m;
    }
    __syncthreads();

    const int c8 = tid & 3;
    const int pq = (tid >> 2) & 1;
    const int hp = (tid >> 3) & 3;
    const int ql = tid >> 5;
    const int gh = hh * 4 + hp;
    const char* basec = (const char*)projb + (gh * 32 + c8 * 8) * 2;
    const int slot0 = (ql << 6) | (hp << 4);

    float a0 = 0, a1 = 0, a2 = 0, a3 = 0, a4 = 0, a5 = 0, a6 = 0, a7 = 0;
#pragma unroll
    for (int l = 0; l < 4; ++l) {
#pragma unroll
        for (int j = 0; j < 2; ++j) {
            const int slot = slot0 | (l << 2) | (pq * 2 + j);
            const int4 m = s_meta[slot];
#pragma unroll
            for (int c = 0; c < 4; ++c) {
                const int pk = (c == 0) ? m.x : (c == 1) ? m.y : (c == 2) ? m.z : m.w;
                const int off = (pk >> 16) << 9;
                const float w = __uint_as_float((unsigned)pk << 16);
                const uint4 v = *(const uint4*)(basec + off);
                a0 += w * __uint_as_float(v.x << 16);
                a1 += w * __uint_as_float(v.x & 0xffff0000u);
                a2 += w * __uint_as_float(v.y << 16);
                a3 += w * __uint_as_float(v.y & 0xffff0000u);
                a4 += w * __uint_as_float(v.z << 16);
                a5 += w * __uint_as_float(v.z & 0xffff0000u);
                a6 += w * __uint_as_float(v.w << 16);
                a7 += w * __uint_as_float(v.w & 0xffff0000u);
            }
        }
    }
    a0 += __shfl_xor(a0, 4); a1 += __shfl_xor(a1, 4);
    a2 += __shfl_xor(a2, 4); a3 += __shfl_xor(a3, 4);
    a4 += __shfl_xor(a4, 4); a5 += __shfl_xor(a5, 4);
    a6 += __shfl_xor(a6, 4); a7 += __shfl_xor(a7, 4);

    if (pq == 0) {
        uint4 o;
        o.x = (unsigned)f2b(a0) | ((unsigned)f2b(a1) << 16);
        o.y = (unsigned)f2b(a2) | ((unsigned)f2b(a3) << 16);
        o.z = (unsigned)f2b(a4) | ((unsigned)f2b(a5) << 16);
        o.w = (unsigned)f2b(a6) | ((unsigned)f2b(a7) << 16);
        *(uint4*)&outpre[(size_t)(q0 + ql) * 256 + gh * 32 + c8 * 8] = o;
    }
}

// ---------------------------------------------------------------------------
// gemm_o: unchanged champion (LDS-free, barrier-free, BM=32, N=256).
// ---------------------------------------------------------------------------
__global__ __launch_bounds__(256) void gemm_o(
    const ushort_t* __restrict__ Ab, const ushort_t* __restrict__ WoT,
    const float* __restrict__ b_out, float* __restrict__ out)
{
    const int bm = blockIdx.x * 32;
    const int tid = threadIdx.x, lane = tid & 63, wave = tid >> 6;
    const int lr = lane & 15, g8 = (lane >> 4) * 8;
    const int rg = (lane >> 4) * 4;

    const ushort_t* ap0;
    const ushort_t* ap1;
    {
        int r0 = bm + lr;      if (r0 >= QTOT) r0 = QTOT - 1;
        int r1 = bm + 16 + lr; if (r1 >= QTOT) r1 = QTOT - 1;
        ap0 = Ab + (size_t)r0 * KD + g8;
        ap1 = Ab + (size_t)r1 * KD + g8;
    }

#pragma unroll
    for (int c = 0; c < 4; ++c) {
        const int col = c * 64 + wave * 16 + lr;
        s16x8 bfr[8];
        {
            const ushort_t* bp = WoT + (size_t)col * KD + g8;
#pragma unroll
            for (int kc = 0; kc < 8; ++kc) bfr[kc] = *(const s16x8*)(bp + kc * 32);
        }
        f32x4 acc[2];
        acc[0] = (f32x4)0.f; acc[1] = (f32x4)0.f;
#pragma unroll
        for (int kc = 0; kc < 8; ++kc) {
            s16x8 a0 = *(const s16x8*)(ap0 + kc * 32);
            s16x8 a1 = *(const s16x8*)(ap1 + kc * 32);
            acc[0] = __builtin_amdgcn_mfma_f32_16x16x32_bf16(a0, bfr[kc], acc[0], 0, 0, 0);
            acc[1] = __builtin_amdgcn_mfma_f32_16x16x32_bf16(a1, bfr[kc], acc[1], 0, 0, 0);
        }
        const float bb = b_out[col];
#pragma unroll
        for (int mf = 0; mf < 2; ++mf)
#pragma unroll
            for (int rr = 0; rr < 4; ++rr) {
                const int row = bm + mf * 16 + rg + rr;
                if (row < QTOT) out[(size_t)row * 256 + col] = acc[mf][rr] + bb;
            }
    }
}

// ---------------------------------------------------------------------------
extern "C" void kernel_launch(void* const* d_in, const int* in_sizes, int n_in,
                              void* d_out, int out_size, void* d_ws, size_t ws_size,
                              hipStream_t stream) {
    const float* query  = (const float*)d_in[0];
    const float* rp     = (const float*)d_in[1];
    const float* inflat = (const float*)d_in[2];
    const float* W_off  = (const float*)d_in[5];
    const float* b_off  = (const float*)d_in[6];
    const float* W_attn = (const float*)d_in[7];
    const float* b_attn = (const float*)d_in[8];
    const float* W_val  = (const float*)d_in[9];
    const float* b_val  = (const float*)d_in[10];
    const float* W_out  = (const float*)d_in[11];
    const float* b_out  = (const float*)d_in[12];
    float* out = (float*)d_out;

    char* ws = (char*)d_ws;
    ushort_t* projb  = (ushort_t*)ws; ws += (size_t)QTOT * 256 * 2;
    ushort_t* offb   = (ushort_t*)ws; ws += (size_t)QTOT * 256 * 2;
    ushort_t* attnb  = (ushort_t*)ws; ws += (size_t)QTOT * 128 * 2;
    ushort_t* outpre = (ushort_t*)ws; ws += (size_t)QTOT * 256 * 2;
    ushort_t* WvT    = (ushort_t*)ws; ws += 65536 * 2;
    ushort_t* WcT    = (ushort_t*)ws; ws += 98304 * 2;
    ushort_t* WoT    = (ushort_t*)ws; ws += 65536 * 2;
    float*    bcomb  = (float*)ws;    ws += 384 * 4;

    prep2<<<dim3(225), dim3(256), 0, stream>>>(W_val, W_off, W_attn, W_out, b_off, b_attn,
                                               WvT, WcT, WoT, bcomb);

    gemm1<<<dim3(510), dim3(256), 0, stream>>>(inflat, query, WvT, WcT, b_val, bcomb,
                                               projb, offb, attnb);

    sample7<<<dim3(3060), dim3(256), 0, stream>>>(rp, offb, attnb, projb, outpre);

    gemm_o<<<dim3(383), dim3(256), 0, stream>>>(outpre, WoT, b_out, out);
}

// Round 20
// 66.539 us; speedup vs baseline: 1.1856x; 1.0053x over previous
//
#include <hip/hip_runtime.h>

#define QTOT 12240
#define KD   256

typedef float f32x4 __attribute__((ext_vector_type(4)));
typedef short s16x8 __attribute__((ext_vector_type(8)));
typedef short s16x4 __attribute__((ext_vector_type(4)));
typedef unsigned short ushort_t;

__device__ __forceinline__ unsigned short f2b(float x) {
    union { float f; unsigned u; } c; c.f = x;
    unsigned r = c.u + 0x7fffu + ((c.u >> 16) & 1u);
    return (unsigned short)(r >> 16);
}
__device__ __forceinline__ float b2f(unsigned short u) {
    return __uint_as_float((unsigned)u << 16);
}
// LDS row: 512B, XOR bits 4-6 of k-byte with row&7 (write & read sides).
__device__ __forceinline__ int swz(int row, int kb) { return row * 512 + (kb ^ ((row & 7) << 4)); }

// ---------------------------------------------------------------------------
// prep2: coalesced weight transpose via 32x32 LDS tiles + combined bias.
// ---------------------------------------------------------------------------
__global__ __launch_bounds__(256) void prep2(
    const float* __restrict__ W_val, const float* __restrict__ W_off,
    const float* __restrict__ W_attn, const float* __restrict__ W_out,
    const float* __restrict__ b_off, const float* __restrict__ b_attn,
    ushort_t* __restrict__ WvT, ushort_t* __restrict__ WcT,
    ushort_t* __restrict__ WoT, float* __restrict__ bcomb)
{
    const int b = blockIdx.x;
    if (b == 224) {
        for (int t = threadIdx.x; t < 384; t += 256)
            bcomb[t] = (t < 256) ? b_off[t] : b_attn[t - 256];
        return;
    }
    __shared__ ushort_t tile[32][33];
    const float* src; ushort_t* dst; int kt, nt, srcld, n_off;
    if (b < 64)       { src = W_val; dst = WvT; kt = b >> 3; nt = b & 7; srcld = 256; n_off = 0; }
    else if (b < 160) { int t = b - 64; dst = WcT; kt = t / 12; nt = t % 12;
                        if (nt < 8) { src = W_off;  srcld = 256; n_off = 0; }
                        else        { src = W_attn; srcld = 128; n_off = 256; } }
    else              { int t = b - 160; src = W_out; dst = WoT; kt = t >> 3; nt = t & 7; srcld = 256; n_off = 0; }

    {   // read 32x32 tile, rows coalesced
        const int r = threadIdx.x >> 3, c4 = (threadIdx.x & 7) * 4;
        const int gk = kt * 32 + r;
        const int gs = nt * 32 + c4 - n_off;
        float4 f = *(const float4*)(src + (size_t)gk * srcld + gs);
        tile[r][c4 + 0] = f2b(f.x); tile[r][c4 + 1] = f2b(f.y);
        tile[r][c4 + 2] = f2b(f.z); tile[r][c4 + 3] = f2b(f.w);
    }
    __syncthreads();
    {   // write transposed, rows coalesced
        const int r2 = threadIdx.x >> 3, k4 = (threadIdx.x & 7) * 4;
        s16x4 v;
        v[0] = tile[k4 + 0][r2]; v[1] = tile[k4 + 1][r2];
        v[2] = tile[k4 + 2][r2]; v[3] = tile[k4 + 3][r2];
        *(s16x4*)(dst + (size_t)(nt * 32 + r2) * 256 + kt * 32 + k4) = v;
    }
}

// ---------------------------------------------------------------------------
// gemm1: BM=48, grid 510 (12240 = 255*48 exactly). A-read-once, 1 barrier,
// B-in-registers single-buffered, fused softmax epilogue. (R19 champion.)
// ---------------------------------------------------------------------------
__global__ __launch_bounds__(256) void gemm1(
    const float* __restrict__ inflat, const float* __restrict__ query,
    const ushort_t* __restrict__ WvT, const ushort_t* __restrict__ WcT,
    const float* __restrict__ b_val, const float* __restrict__ bcomb,
    ushort_t* __restrict__ projb, ushort_t* __restrict__ offb,
    ushort_t* __restrict__ attnb)
{
    __shared__ char As[24576];
    const int b = blockIdx.x;
    const bool isval = b < 255;
    const int bm = (isval ? b : b - 255) * 48;
    const float* A = isval ? inflat : query;
    const ushort_t* WT = isval ? WvT : WcT;
    const int nc = isval ? 4 : 6;

    const int tid = threadIdx.x, lane = tid & 63, wave = tid >> 6;
    const int lr = lane & 15, g8 = (lane >> 4) * 8;

    {   // stage A panel: 48 rows x 256 k, f32 -> bf16; linear coalesced map
        const float4* srcb = (const float4*)(A + (size_t)bm * KD);
#pragma unroll
        for (int j = 0; j < 12; ++j) {
            const int f4i = j * 256 + tid;
            const int row = f4i >> 6;
            const int colb = (f4i & 63) * 8;
            float4 f = srcb[f4i];
            s16x4 v;
            v[0] = f2b(f.x); v[1] = f2b(f.y); v[2] = f2b(f.z); v[3] = f2b(f.w);
            *(s16x4*)(As + swz(row, colb)) = v;
        }
    }
    __syncthreads();

    const int rg = (lane >> 4) * 4;

    for (int c = 0; c < nc; ++c) {
        const int col = c * 64 + wave * 16 + lr;
        s16x8 bfr[8];
        {
            const ushort_t* bp = WT + (size_t)col * KD + g8;
#pragma unroll
            for (int kc = 0; kc < 8; ++kc) bfr[kc] = *(const s16x8*)(bp + kc * 32);
        }
        f32x4 acc0 = (f32x4)0.f, acc1 = (f32x4)0.f, acc2 = (f32x4)0.f;
#pragma unroll
        for (int kc = 0; kc < 8; ++kc) {
            const int kb = (kc * 32 + g8) * 2;
            s16x8 a0 = *(const s16x8*)(As + swz(lr,      kb));
            s16x8 a1 = *(const s16x8*)(As + swz(16 + lr, kb));
            s16x8 a2 = *(const s16x8*)(As + swz(32 + lr, kb));
            acc0 = __builtin_amdgcn_mfma_f32_16x16x32_bf16(a0, bfr[kc], acc0, 0, 0, 0);
            acc1 = __builtin_amdgcn_mfma_f32_16x16x32_bf16(a1, bfr[kc], acc1, 0, 0, 0);
            acc2 = __builtin_amdgcn_mfma_f32_16x16x32_bf16(a2, bfr[kc], acc2, 0, 0, 0);
        }
        const float bb = isval ? b_val[col] : bcomb[col];

        if (!isval && c >= 4) {
            const int gh = (c - 4) * 4 + wave;       // global head 0..7
            float v[3][4], m[3][4], e[3][4], s[3][4];
#pragma unroll
            for (int rr = 0; rr < 4; ++rr) {
                v[0][rr] = acc0[rr] + bb; v[1][rr] = acc1[rr] + bb; v[2][rr] = acc2[rr] + bb;
            }
#pragma unroll
            for (int mf = 0; mf < 3; ++mf)
#pragma unroll
                for (int rr = 0; rr < 4; ++rr) m[mf][rr] = v[mf][rr];
#pragma unroll
            for (int d = 1; d < 16; d <<= 1)
#pragma unroll
                for (int mf = 0; mf < 3; ++mf)
#pragma unroll
                    for (int rr = 0; rr < 4; ++rr) m[mf][rr] = fmaxf(m[mf][rr], __shfl_xor(m[mf][rr], d));
#pragma unroll
            for (int mf = 0; mf < 3; ++mf)
#pragma unroll
                for (int rr = 0; rr < 4; ++rr) { e[mf][rr] = __expf(v[mf][rr] - m[mf][rr]); s[mf][rr] = e[mf][rr]; }
#pragma unroll
            for (int d = 1; d < 16; d <<= 1)
#pragma unroll
                for (int mf = 0; mf < 3; ++mf)
#pragma unroll
                    for (int rr = 0; rr < 4; ++rr) s[mf][rr] += __shfl_xor(s[mf][rr], d);
#pragma unroll
            for (int mf = 0; mf < 3; ++mf)
#pragma unroll
                for (int rr = 0; rr < 4; ++rr)
                    attnb[(size_t)(bm + mf * 16 + rg + rr) * 128 + gh * 16 + lr] =
                        f2b(e[mf][rr] / s[mf][rr]);
        } else {
#pragma unroll
            for (int mf = 0; mf < 3; ++mf) {
                const f32x4& a = (mf == 0) ? acc0 : (mf == 1) ? acc1 : acc2;
#pragma unroll
                for (int rr = 0; rr < 4; ++rr) {
                    const int row = bm + mf * 16 + rg + rr;
                    const float v = a[rr] + bb;
                    if (isval) projb[(size_t)row * 256 + col] = f2b(v);
                    else       offb [(size_t)row * 256 + col] = f2b(v);
                }
            }
        }
    }
}

// ---------------------------------------------------------------------------
// sample7: unchanged (packed int4 metadata, head-half split,
// launch_bounds(256,2), hardcoded spatial shapes).
// ---------------------------------------------------------------------------
__global__ __launch_bounds__(256, 2) void sample7(
    const float* __restrict__ rp, const ushort_t* __restrict__ offb,
    const ushort_t* __restrict__ attnb, const ushort_t* __restrict__ projb,
    ushort_t* __restrict__ outpre)
{
    const int bid = blockIdx.x;
    const int hh = (bid >= 1530) ? 1 : 0;       // head-half (slow index)
    const int g  = hh ? (bid - 1530) : bid;     // query group
    const int q0 = g * 8;
    const int tid = threadIdx.x;

    __shared__ int4 s_meta[512];                // [ql][hp][lp] packed corners

#pragma unroll
    for (int rep = 0; rep < 2; ++rep) {
        const int task = rep * 256 + tid;
        const int ql = task >> 6;
        const int hp = (task >> 4) & 3;
        const int lp = task & 15;
        const int l = lp >> 2;
        const int q = q0 + ql;
        const int gh = hh * 4 + hp;
        const int t128 = gh * 16 + lp;

        const float aw = b2f(attnb[(size_t)q * 128 + t128]);

        const unsigned opk = *(const unsigned*)&offb[(size_t)q * 256 + t128 * 2];
        const float ox = __uint_as_float(opk << 16);
        const float oy = __uint_as_float(opk & 0xffff0000u);

        const int Wl = 96 >> l;                  // = Hl (fixed problem shapes)
        const int st = 12288 - (12288 >> (2 * l));
        const float rx = rp[((size_t)q * 4 + l) * 2 + 0];
        const float ry = rp[((size_t)q * 4 + l) * 2 + 1];

        const float x = rx * (float)Wl + ox - 0.5f;
        const float y = ry * (float)Wl + oy - 0.5f;
        const float xf = floorf(x), yf = floorf(y);
        const int x0 = (int)xf, y0 = (int)yf;
        const float lx = x - xf, ly = y - yf;

        const bool vx0 = (x0 >= 0) && (x0 < Wl);
        const bool vx1 = (x0 + 1 >= 0) && (x0 + 1 < Wl);
        const bool vy0 = (y0 >= 0) && (y0 < Wl);
        const bool vy1 = (y0 + 1 >= 0) && (y0 + 1 < Wl);

        const float w00 = (vx0 && vy0) ? aw * (1.f - ly) * (1.f - lx) : 0.f;
        const float w01 = (vx1 && vy0) ? aw * (1.f - ly) * lx         : 0.f;
        const float w10 = (vx0 && vy1) ? aw * ly * (1.f - lx)         : 0.f;
        const float w11 = (vx1 && vy1) ? aw * ly * lx                 : 0.f;
        const int i00 = (vx0 && vy0) ? st + y0 * Wl + x0           : 0;
        const int i01 = (vx1 && vy0) ? st + y0 * Wl + x0 + 1       : 0;
        const int i10 = (vx0 && vy1) ? st + (y0 + 1) * Wl + x0     : 0;
        const int i11 = (vx1 && vy1) ? st + (y0 + 1) * Wl + x0 + 1 : 0;

        int4 m;
        m.x = (i00 << 16) | (int)f2b(w00);
        m.y = (i01 << 16) | (int)f2b(w01);
        m.z = (i10 << 16) | (int)f2b(w10);
        m.w = (i11 << 16) | (int)f2b(w11);
        s_meta[task] = m;
    }
    __syncthreads();

    const int c8 = tid & 3;
    const int pq = (tid >> 2) & 1;
    const int hp = (tid >> 3) & 3;
    const int ql = tid >> 5;
    const int gh = hh * 4 + hp;
    const char* basec = (const char*)projb + (gh * 32 + c8 * 8) * 2;
    const int slot0 = (ql << 6) | (hp << 4);

    float a0 = 0, a1 = 0, a2 = 0, a3 = 0, a4 = 0, a5 = 0, a6 = 0, a7 = 0;
#pragma unroll
    for (int l = 0; l < 4; ++l) {
#pragma unroll
        for (int j = 0; j < 2; ++j) {
            const int slot = slot0 | (l << 2) | (pq * 2 + j);
            const int4 m = s_meta[slot];
#pragma unroll
            for (int c = 0; c < 4; ++c) {
                const int pk = (c == 0) ? m.x : (c == 1) ? m.y : (c == 2) ? m.z : m.w;
                const int off = (pk >> 16) << 9;
                const float w = __uint_as_float((unsigned)pk << 16);
                const uint4 v = *(const uint4*)(basec + off);
                a0 += w * __uint_as_float(v.x << 16);
                a1 += w * __uint_as_float(v.x & 0xffff0000u);
                a2 += w * __uint_as_float(v.y << 16);
                a3 += w * __uint_as_float(v.y & 0xffff0000u);
                a4 += w * __uint_as_float(v.z << 16);
                a5 += w * __uint_as_float(v.z & 0xffff0000u);
                a6 += w * __uint_as_float(v.w << 16);
                a7 += w * __uint_as_float(v.w & 0xffff0000u);
            }
        }
    }
    a0 += __shfl_xor(a0, 4); a1 += __shfl_xor(a1, 4);
    a2 += __shfl_xor(a2, 4); a3 += __shfl_xor(a3, 4);
    a4 += __shfl_xor(a4, 4); a5 += __shfl_xor(a5, 4);
    a6 += __shfl_xor(a6, 4); a7 += __shfl_xor(a7, 4);

    if (pq == 0) {
        uint4 o;
        o.x = (unsigned)f2b(a0) | ((unsigned)f2b(a1) << 16);
        o.y = (unsigned)f2b(a2) | ((unsigned)f2b(a3) << 16);
        o.z = (unsigned)f2b(a4) | ((unsigned)f2b(a5) << 16);
        o.w = (unsigned)f2b(a6) | ((unsigned)f2b(a7) << 16);
        *(uint4*)&outpre[(size_t)(q0 + ql) * 256 + gh * 32 + c8 * 8] = o;
    }
}

// ---------------------------------------------------------------------------
// gemm_o: LDS-free, barrier-free; grid 766 = 383 m-tiles x 2 n-halves,
// 2 chunks/block -> 3 blocks/CU, 12 waves/CU (2x the independent B-chains
// in flight vs the 383-block version).
// ---------------------------------------------------------------------------
__global__ __launch_bounds__(256) void gemm_o(
    const ushort_t* __restrict__ Ab, const ushort_t* __restrict__ WoT,
    const float* __restrict__ b_out, float* __restrict__ out)
{
    const int bid = blockIdx.x;
    const int bm = (bid >> 1) * 32;
    const int nh = bid & 1;                    // n-half: cols [nh*128, nh*128+128)
    const int tid = threadIdx.x, lane = tid & 63, wave = tid >> 6;
    const int lr = lane & 15, g8 = (lane >> 4) * 8;
    const int rg = (lane >> 4) * 4;

    const ushort_t* ap0;
    const ushort_t* ap1;
    {
        int r0 = bm + lr;      if (r0 >= QTOT) r0 = QTOT - 1;
        int r1 = bm + 16 + lr; if (r1 >= QTOT) r1 = QTOT - 1;
        ap0 = Ab + (size_t)r0 * KD + g8;
        ap1 = Ab + (size_t)r1 * KD + g8;
    }

#pragma unroll
    for (int c = 0; c < 2; ++c) {
        const int col = nh * 128 + c * 64 + wave * 16 + lr;
        s16x8 bfr[8];
        {
            const ushort_t* bp = WoT + (size_t)col * KD + g8;
#pragma unroll
            for (int kc = 0; kc < 8; ++kc) bfr[kc] = *(const s16x8*)(bp + kc * 32);
        }
        f32x4 acc[2];
        acc[0] = (f32x4)0.f; acc[1] = (f32x4)0.f;
#pragma unroll
        for (int kc = 0; kc < 8; ++kc) {
            s16x8 a0 = *(const s16x8*)(ap0 + kc * 32);
            s16x8 a1 = *(const s16x8*)(ap1 + kc * 32);
            acc[0] = __builtin_amdgcn_mfma_f32_16x16x32_bf16(a0, bfr[kc], acc[0], 0, 0, 0);
            acc[1] = __builtin_amdgcn_mfma_f32_16x16x32_bf16(a1, bfr[kc], acc[1], 0, 0, 0);
        }
        const float bb = b_out[col];
#pragma unroll
        for (int mf = 0; mf < 2; ++mf)
#pragma unroll
            for (int rr = 0; rr < 4; ++rr) {
                const int row = bm + mf * 16 + rg + rr;
                if (row < QTOT) out[(size_t)row * 256 + col] = acc[mf][rr] + bb;
            }
    }
}

// ---------------------------------------------------------------------------
extern "C" void kernel_launch(void* const* d_in, const int* in_sizes, int n_in,
                              void* d_out, int out_size, void* d_ws, size_t ws_size,
                              hipStream_t stream) {
    const float* query  = (const float*)d_in[0];
    const float* rp     = (const float*)d_in[1];
    const float* inflat = (const float*)d_in[2];
    const float* W_off  = (const float*)d_in[5];
    const float* b_off  = (const float*)d_in[6];
    const float* W_attn = (const float*)d_in[7];
    const float* b_attn = (const float*)d_in[8];
    const float* W_val  = (const float*)d_in[9];
    const float* b_val  = (const float*)d_in[10];
    const float* W_out  = (const float*)d_in[11];
    const float* b_out  = (const float*)d_in[12];
    float* out = (float*)d_out;

    char* ws = (char*)d_ws;
    ushort_t* projb  = (ushort_t*)ws; ws += (size_t)QTOT * 256 * 2;
    ushort_t* offb   = (ushort_t*)ws; ws += (size_t)QTOT * 256 * 2;
    ushort_t* attnb  = (ushort_t*)ws; ws += (size_t)QTOT * 128 * 2;
    ushort_t* outpre = (ushort_t*)ws; ws += (size_t)QTOT * 256 * 2;
    ushort_t* WvT    = (ushort_t*)ws; ws += 65536 * 2;
    ushort_t* WcT    = (ushort_t*)ws; ws += 98304 * 2;
    ushort_t* WoT    = (ushort_t*)ws; ws += 65536 * 2;
    float*    bcomb  = (float*)ws;    ws += 384 * 4;

    prep2<<<dim3(225), dim3(256), 0, stream>>>(W_val, W_off, W_attn, W_out, b_off, b_attn,
                                               WvT, WcT, WoT, bcomb);

    gemm1<<<dim3(510), dim3(256), 0, stream>>>(inflat, query, WvT, WcT, b_val, bcomb,
                                               projb, offb, attnb);

    sample7<<<dim3(3060), dim3(256), 0, stream>>>(rp, offb, attnb, projb, outpre);

    gemm_o<<<dim3(766), dim3(256), 0, stream>>>(outpre, WoT, b_out, out);
}